// Round 1
// baseline (277.144 us; speedup 1.0000x reference)
//
#include <hip/hip_runtime.h>
#include <math.h>

// ---------------------------------------------------------------------------
// AttentiveFPModule: knn(K=3) attentive interpolate + concat + Linear + BN + LeakyReLU
// Sizes (from setup_inputs): Nx=4096, Ny=16384, C=256, Cs=128, Co=256, B=4
// ---------------------------------------------------------------------------

#define KNEI 3
#define BM 64
#define BN 64
#define BK 64

__device__ __forceinline__ bool nless(float da, int ia, float db, int ib) {
    return (da < db) || (da == db && ia < ib);
}

__device__ __forceinline__ void ins3(float dd, int j,
                                     float& d0, int& i0,
                                     float& d1, int& i1,
                                     float& d2, int& i2) {
    if (nless(dd, j, d2, i2)) {
        if (nless(dd, j, d1, i1)) {
            d2 = d1; i2 = i1;
            if (nless(dd, j, d0, i0)) { d1 = d0; i1 = i0; d0 = dd; i0 = j; }
            else                      { d1 = dd; i1 = j; }
        } else { d2 = dd; i2 = j; }
    }
}

// K0a: attv[j] = dot(x[j], w_att); xsq[j] = |pos[j]|^2.  One wave per row.
__global__ void k_prep(const float* __restrict__ x, const float* __restrict__ pos,
                       const float* __restrict__ w_att,
                       float* __restrict__ attv, float* __restrict__ xsq,
                       int Nx, int C) {
    int wid  = (blockIdx.x * blockDim.x + threadIdx.x) >> 6;
    int lane = threadIdx.x & 63;
    if (wid >= Nx) return;
    float s = 0.f;
    for (int k = lane * 4; k < C; k += 256) {
        float4 xv = *reinterpret_cast<const float4*>(x + (size_t)wid * C + k);
        float4 wv = *reinterpret_cast<const float4*>(w_att + k);
        s += xv.x * wv.x + xv.y * wv.y + xv.z * wv.z + xv.w * wv.w;
    }
    #pragma unroll
    for (int off = 32; off; off >>= 1) s += __shfl_xor(s, off);
    if (lane == 0) {
        attv[wid] = s;
        float px = pos[wid * 3], py = pos[wid * 3 + 1], pz = pos[wid * 3 + 2];
        xsq[wid] = px * px + py * py + pz * pz;
    }
}

// K0b: start[b] = lower_bound(batch, b) for b in [0, NB]; batch is sorted.
__global__ void k_start(const int* __restrict__ batch, int* __restrict__ start,
                        int Nx, int NB) {
    int b = threadIdx.x;
    if (b > NB) return;
    int lo = 0, hi = Nx;
    while (lo < hi) {
        int mid = (lo + hi) >> 1;
        if (batch[mid] < b) lo = mid + 1; else hi = mid;
    }
    start[b] = lo;
}

// K1: one wave per y point. Lane-strided segment scan -> local top-3 ->
// butterfly merge -> lane 0 computes fused coefficients.
__global__ void k_knn(const float* __restrict__ pos, const float* __restrict__ xsq,
                      const float* __restrict__ attv,
                      const float* __restrict__ pos_skip,
                      const int* __restrict__ batch_skip,
                      const int* __restrict__ start,
                      int* __restrict__ knn_idx, float* __restrict__ knn_coef,
                      int Ny) {
    int wib  = threadIdx.x >> 6;
    int lane = threadIdx.x & 63;
    int i = blockIdx.x * (blockDim.x >> 6) + wib;
    if (i >= Ny) return;

    float py0 = pos_skip[i * 3], py1 = pos_skip[i * 3 + 1], py2 = pos_skip[i * 3 + 2];
    int b = batch_skip[i];
    int s = start[b], e = start[b + 1];
    float ysq = py0 * py0 + py1 * py1 + py2 * py2;

    float d0 = 3.4e38f, d1 = 3.4e38f, d2 = 3.4e38f;
    int   i0 = 0x7fffffff, i1 = 0x7fffffff, i2 = 0x7fffffff;

    for (int j = s + lane; j < e; j += 64) {
        float qx = pos[j * 3], qy = pos[j * 3 + 1], qz = pos[j * 3 + 2];
        float dot = py0 * qx + py1 * qy + py2 * qz;
        float dd = (ysq + xsq[j]) - 2.f * dot;
        ins3(dd, j, d0, i0, d1, i1, d2, i2);
    }

    #pragma unroll
    for (int off = 1; off < 64; off <<= 1) {
        float e0 = __shfl_xor(d0, off), e1 = __shfl_xor(d1, off), e2 = __shfl_xor(d2, off);
        int   j0 = __shfl_xor(i0, off), j1 = __shfl_xor(i1, off), j2 = __shfl_xor(i2, off);
        ins3(e0, j0, d0, i0, d1, i1, d2, i2);
        ins3(e1, j1, d0, i0, d1, i1, d2, i2);
        ins3(e2, j2, d0, i0, d1, i1, d2, i2);
    }

    if (lane == 0) {
        int   jj[3] = { i0, i1, i2 };
        float w[3], a[3];
        #pragma unroll
        for (int t = 0; t < KNEI; ++t) {
            int j = (jj[t] == 0x7fffffff) ? 0 : jj[t];
            jj[t] = j;
            float dx = pos[j * 3]     - py0;
            float dy = pos[j * 3 + 1] - py1;
            float dz = pos[j * 3 + 2] - py2;
            float sqd = dx * dx + dy * dy + dz * dz;
            w[t] = 1.f / fmaxf(sqd, 1e-16f);
            a[t] = attv[j];
        }
        float m  = fmaxf(a[0], fmaxf(a[1], a[2]));
        float e0s = expf(a[0] - m), e1s = expf(a[1] - m), e2s = expf(a[2] - m);
        float se  = e0s + e1s + e2s;
        float den = w[0] + w[1] + w[2];
        float inv = 1.f / (se * den);
        float c[3] = { w[0] * e0s * inv, w[1] * e1s * inv, w[2] * e2s * inv };
        #pragma unroll
        for (int t = 0; t < KNEI; ++t) {
            knn_idx[i * 3 + t]  = jj[t];
            knn_coef[i * 3 + t] = c[t];
        }
    }
}

// K2: h = [y || x_skip] @ W1 + b1, with y-rows synthesized on the fly from the
// 3-neighbor gather. Also emits per-block column partial sum/sumsq for BN.
__global__ __launch_bounds__(256) void k_gemm(
    const float* __restrict__ x, const float* __restrict__ x_skip,
    const float* __restrict__ W1, const float* __restrict__ b1,
    const int* __restrict__ knn_idx, const float* __restrict__ knn_coef,
    float* __restrict__ hbuf, float* __restrict__ psum, float* __restrict__ psq,
    int Ny, int C, int Cs, int Co) {
    __shared__ __align__(16) float As[BM][BK + 4];
    __shared__ __align__(16) float Bs[BK][BN + 4];

    const int mt = blockIdx.x, nt = blockIdx.y;
    const int rowbase = mt * BM, ncb = nt * BN;
    const int tid = threadIdx.x;
    const int tx = tid & 15, ty = tid >> 4;
    const int r = tid >> 2, q = tid & 3;   // staging: 4 threads per row/k
    const int Kin = C + Cs;

    // gather metadata for staging row r
    const int grow = rowbase + r;
    const int   gi0 = knn_idx[grow * 3 + 0];
    const int   gi1 = knn_idx[grow * 3 + 1];
    const int   gi2 = knn_idx[grow * 3 + 2];
    const float gc0 = knn_coef[grow * 3 + 0];
    const float gc1 = knn_coef[grow * 3 + 1];
    const float gc2 = knn_coef[grow * 3 + 2];

    float acc[4][4] = {};

    for (int k0 = 0; k0 < Kin; k0 += BK) {
        // ---- stage A tile (64 rows x 64 k) ----
        if (k0 < C) {
            #pragma unroll
            for (int u = 0; u < 4; ++u) {
                int c = q * 16 + u * 4;
                float4 v0 = *reinterpret_cast<const float4*>(x + (size_t)gi0 * C + k0 + c);
                float4 v1 = *reinterpret_cast<const float4*>(x + (size_t)gi1 * C + k0 + c);
                float4 v2 = *reinterpret_cast<const float4*>(x + (size_t)gi2 * C + k0 + c);
                float4 o;
                o.x = gc0 * v0.x + gc1 * v1.x + gc2 * v2.x;
                o.y = gc0 * v0.y + gc1 * v1.y + gc2 * v2.y;
                o.z = gc0 * v0.z + gc1 * v1.z + gc2 * v2.z;
                o.w = gc0 * v0.w + gc1 * v1.w + gc2 * v2.w;
                *reinterpret_cast<float4*>(&As[r][c]) = o;
            }
        } else {
            #pragma unroll
            for (int u = 0; u < 4; ++u) {
                int c = q * 16 + u * 4;
                *reinterpret_cast<float4*>(&As[r][c]) =
                    *reinterpret_cast<const float4*>(x_skip + (size_t)grow * Cs + (k0 - C) + c);
            }
        }
        // ---- stage B tile (64 k x 64 n) ----
        #pragma unroll
        for (int u = 0; u < 4; ++u) {
            int c = q * 16 + u * 4;
            *reinterpret_cast<float4*>(&Bs[r][c]) =
                *reinterpret_cast<const float4*>(W1 + (size_t)(k0 + r) * Co + ncb + c);
        }
        __syncthreads();

        #pragma unroll 8
        for (int kk = 0; kk < BK; ++kk) {
            float a0 = As[ty * 4 + 0][kk];
            float a1 = As[ty * 4 + 1][kk];
            float a2 = As[ty * 4 + 2][kk];
            float a3 = As[ty * 4 + 3][kk];
            float4 bv = *reinterpret_cast<const float4*>(&Bs[kk][tx * 4]);
            acc[0][0] += a0 * bv.x; acc[0][1] += a0 * bv.y; acc[0][2] += a0 * bv.z; acc[0][3] += a0 * bv.w;
            acc[1][0] += a1 * bv.x; acc[1][1] += a1 * bv.y; acc[1][2] += a1 * bv.z; acc[1][3] += a1 * bv.w;
            acc[2][0] += a2 * bv.x; acc[2][1] += a2 * bv.y; acc[2][2] += a2 * bv.z; acc[2][3] += a2 * bv.w;
            acc[3][0] += a3 * bv.x; acc[3][1] += a3 * bv.y; acc[3][2] += a3 * bv.z; acc[3][3] += a3 * bv.w;
        }
        __syncthreads();
    }

    // ---- epilogue: +bias, write h, per-thread column stats ----
    float bb[4];
    #pragma unroll
    for (int n = 0; n < 4; ++n) bb[n] = b1[ncb + tx * 4 + n];

    float csum[4] = {}, csq[4] = {};
    #pragma unroll
    for (int m = 0; m < 4; ++m) {
        float4 hv;
        hv.x = acc[m][0] + bb[0];
        hv.y = acc[m][1] + bb[1];
        hv.z = acc[m][2] + bb[2];
        hv.w = acc[m][3] + bb[3];
        *reinterpret_cast<float4*>(hbuf + (size_t)(rowbase + ty * 4 + m) * Co + ncb + tx * 4) = hv;
        csum[0] += hv.x; csum[1] += hv.y; csum[2] += hv.z; csum[3] += hv.w;
        csq[0] += hv.x * hv.x; csq[1] += hv.y * hv.y; csq[2] += hv.z * hv.z; csq[3] += hv.w * hv.w;
    }

    // deterministic in-block reduction over ty (reuse As as scratch)
    __syncthreads();
    float* red = &As[0][0];  // 16*16*8 floats
    #pragma unroll
    for (int n = 0; n < 4; ++n) {
        red[(ty * 16 + tx) * 8 + n]     = csum[n];
        red[(ty * 16 + tx) * 8 + 4 + n] = csq[n];
    }
    __syncthreads();
    if (ty == 0) {
        float s[4] = {}, qq[4] = {};
        for (int yy = 0; yy < 16; ++yy) {
            #pragma unroll
            for (int n = 0; n < 4; ++n) {
                s[n]  += red[(yy * 16 + tx) * 8 + n];
                qq[n] += red[(yy * 16 + tx) * 8 + 4 + n];
            }
        }
        #pragma unroll
        for (int n = 0; n < 4; ++n) {
            psum[(size_t)mt * Co + ncb + tx * 4 + n] = s[n];
            psq [(size_t)mt * Co + ncb + tx * 4 + n] = qq[n];
        }
    }
}

// K3: reduce partials -> mean/var -> scale/shift per channel (1 block)
__global__ void k_stats(const float* __restrict__ psum, const float* __restrict__ psq,
                        const float* __restrict__ gamma, const float* __restrict__ beta,
                        float* __restrict__ scale, float* __restrict__ shift,
                        int mtiles, int Co, int Ny) {
    int c = threadIdx.x;
    if (c >= Co) return;
    float s = 0.f, q = 0.f;
    for (int m = 0; m < mtiles; ++m) {
        s += psum[(size_t)m * Co + c];
        q += psq [(size_t)m * Co + c];
    }
    float mean = s / (float)Ny;
    float var  = q / (float)Ny - mean * mean;
    float rstd = rsqrtf(var + 1e-6f);
    float sc = gamma[c] * rstd;
    scale[c] = sc;
    shift[c] = beta[c] - mean * sc;
}

// K4: in-place BN apply + LeakyReLU over h (float4)
__global__ void k_final(float* __restrict__ h, const float* __restrict__ scale,
                        const float* __restrict__ shift, int total4, int Co) {
    int t = blockIdx.x * blockDim.x + threadIdx.x;
    if (t >= total4) return;
    int c4 = (t & (Co / 4 - 1)) * 4;
    float4 v  = *reinterpret_cast<float4*>(h + (size_t)t * 4);
    float4 sc = *reinterpret_cast<const float4*>(scale + c4);
    float4 sh = *reinterpret_cast<const float4*>(shift + c4);
    v.x = v.x * sc.x + sh.x; v.x = v.x > 0.f ? v.x : 0.2f * v.x;
    v.y = v.y * sc.y + sh.y; v.y = v.y > 0.f ? v.y : 0.2f * v.y;
    v.z = v.z * sc.z + sh.z; v.z = v.z > 0.f ? v.z : 0.2f * v.z;
    v.w = v.w * sc.w + sh.w; v.w = v.w > 0.f ? v.w : 0.2f * v.w;
    *reinterpret_cast<float4*>(h + (size_t)t * 4) = v;
}

// K5: tail outputs: pos_skip copy + batch_skip as float
__global__ void k_tail(const float* __restrict__ pos_skip,
                       const int* __restrict__ batch_skip,
                       float* __restrict__ out_tail, int Ny) {
    int t = blockIdx.x * blockDim.x + threadIdx.x;
    int n3 = Ny * 3;
    if (t < n3) out_tail[t] = pos_skip[t];
    else if (t < n3 + Ny) out_tail[t] = (float)batch_skip[t - n3];
}

extern "C" void kernel_launch(void* const* d_in, const int* in_sizes, int n_in,
                              void* d_out, int out_size, void* d_ws, size_t ws_size,
                              hipStream_t stream) {
    const float* x         = (const float*)d_in[0];
    const float* pos       = (const float*)d_in[1];
    const int*   batch     = (const int*)d_in[2];
    const float* x_skip    = (const float*)d_in[3];
    const float* pos_skip  = (const float*)d_in[4];
    const int*   batch_skip= (const int*)d_in[5];
    const float* w_att     = (const float*)d_in[6];
    const float* W1        = (const float*)d_in[7];
    const float* b1        = (const float*)d_in[8];
    const float* gamma     = (const float*)d_in[9];
    const float* beta      = (const float*)d_in[10];

    const int Nx = in_sizes[2];
    const int Ny = in_sizes[5];
    const int C  = in_sizes[6];
    const int Co = in_sizes[8];
    const int Cs = in_sizes[3] / Ny;
    const int NB = 8;
    const int mtiles = Ny / BM;
    const int ntiles = Co / BN;

    char* w = (char*)d_ws;
    int*   start    = (int*)w;   w += 64;
    float* attv     = (float*)w; w += (size_t)Nx * 4;
    float* xsq      = (float*)w; w += (size_t)Nx * 4;
    int*   knn_idx  = (int*)w;   w += (size_t)Ny * 3 * 4;
    float* knn_coef = (float*)w; w += (size_t)Ny * 3 * 4;
    float* psum     = (float*)w; w += (size_t)mtiles * Co * 4;
    float* psq      = (float*)w; w += (size_t)mtiles * Co * 4;
    float* scale    = (float*)w; w += (size_t)Co * 4;
    float* shift    = (float*)w; w += (size_t)Co * 4;

    float* out      = (float*)d_out;
    float* hbuf     = out;                       // [Ny, Co]
    float* out_tail = out + (size_t)Ny * Co;     // pos_skip + batch_skip

    k_prep<<<dim3((Nx + 3) / 4), dim3(256), 0, stream>>>(x, pos, w_att, attv, xsq, Nx, C);
    k_start<<<dim3(1), dim3(64), 0, stream>>>(batch, start, Nx, NB);
    k_knn<<<dim3((Ny + 3) / 4), dim3(256), 0, stream>>>(pos, xsq, attv, pos_skip, batch_skip,
                                                        start, knn_idx, knn_coef, Ny);
    k_gemm<<<dim3(mtiles, ntiles), dim3(256), 0, stream>>>(x, x_skip, W1, b1, knn_idx, knn_coef,
                                                           hbuf, psum, psq, Ny, C, Cs, Co);
    k_stats<<<dim3(1), dim3(256), 0, stream>>>(psum, psq, gamma, beta, scale, shift, mtiles, Co, Ny);
    k_final<<<dim3((Ny * Co / 4 + 255) / 256), dim3(256), 0, stream>>>(hbuf, scale, shift, Ny * Co / 4, Co);
    k_tail<<<dim3((Ny * 4 + 255) / 256), dim3(256), 0, stream>>>(pos_skip, batch_skip, out_tail, Ny);
}

// Round 2
// 138.888 us; speedup vs baseline: 1.9955x; 1.9955x over previous
//
#include <hip/hip_runtime.h>
#include <math.h>

// ---------------------------------------------------------------------------
// AttentiveFPModule: knn(K=3) attentive interpolate + concat + Linear + BN + LeakyReLU
// Sizes (from setup_inputs): Nx=4096, Ny=16384, C=256, Cs=128, Co=256, B=4
// ---------------------------------------------------------------------------

#define KNEI 3
#define BM 64
#define BN 64
#define BK 64
#define GL 8   // lanes per y-point in k_knn

__device__ __forceinline__ bool nless(float da, int ia, float db, int ib) {
    return (da < db) || (da == db && ia < ib);
}

// Branchless insert, strict-less only (scan phase: per-lane candidates come in
// increasing index order, so '<' keeps the earliest index on ties).
__device__ __forceinline__ void ins3f(float dd, int j,
                                      float& d0, int& i0,
                                      float& d1, int& i1,
                                      float& d2, int& i2) {
    bool l0 = dd < d0;
    bool l1 = dd < d1;
    bool l2 = dd < d2;
    float n2 = l1 ? d1 : (l2 ? dd : d2); int m2 = l1 ? i1 : (l2 ? j : i2);
    float n1 = l0 ? d0 : (l1 ? dd : d1); int m1 = l0 ? i0 : (l1 ? j : i1);
    float n0 = l0 ? dd : d0;             int m0 = l0 ? j  : i0;
    d0 = n0; i0 = m0; d1 = n1; i1 = m1; d2 = n2; i2 = m2;
}

// Branchless insert with index tie-break (merge phase).
__device__ __forceinline__ void ins3t(float dd, int j,
                                      float& d0, int& i0,
                                      float& d1, int& i1,
                                      float& d2, int& i2) {
    bool l0 = nless(dd, j, d0, i0);
    bool l1 = nless(dd, j, d1, i1);
    bool l2 = nless(dd, j, d2, i2);
    float n2 = l1 ? d1 : (l2 ? dd : d2); int m2 = l1 ? i1 : (l2 ? j : i2);
    float n1 = l0 ? d0 : (l1 ? dd : d1); int m1 = l0 ? i0 : (l1 ? j : i1);
    float n0 = l0 ? dd : d0;             int m0 = l0 ? j  : i0;
    d0 = n0; i0 = m0; d1 = n1; i1 = m1; d2 = n2; i2 = m2;
}

// K0a: attv[j] = dot(x[j], w_att); pos4[j] = (pos, |pos|^2). One wave per row.
__global__ void k_prep(const float* __restrict__ x, const float* __restrict__ pos,
                       const float* __restrict__ w_att,
                       float* __restrict__ attv, float4* __restrict__ pos4,
                       int Nx, int C) {
    int wid  = (blockIdx.x * blockDim.x + threadIdx.x) >> 6;
    int lane = threadIdx.x & 63;
    if (wid >= Nx) return;
    float s = 0.f;
    for (int k = lane * 4; k < C; k += 256) {
        float4 xv = *reinterpret_cast<const float4*>(x + (size_t)wid * C + k);
        float4 wv = *reinterpret_cast<const float4*>(w_att + k);
        s += xv.x * wv.x + xv.y * wv.y + xv.z * wv.z + xv.w * wv.w;
    }
    #pragma unroll
    for (int off = 32; off; off >>= 1) s += __shfl_xor(s, off);
    if (lane == 0) {
        attv[wid] = s;
        float px = pos[wid * 3], py = pos[wid * 3 + 1], pz = pos[wid * 3 + 2];
        pos4[wid] = make_float4(px, py, pz, px * px + py * py + pz * pz);
    }
}

// K0b: start[b] = lower_bound(batch, b) for b in [0, NB]; batch is sorted.
__global__ void k_start(const int* __restrict__ batch, int* __restrict__ start,
                        int Nx, int NB) {
    int b = threadIdx.x;
    if (b > NB) return;
    int lo = 0, hi = Nx;
    while (lo < hi) {
        int mid = (lo + hi) >> 1;
        if (batch[mid] < b) lo = mid + 1; else hi = mid;
    }
    start[b] = lo;
}

// K1: GL lanes per y point. Branchless lane-strided scan (float4 candidates),
// 3-stage butterfly merge, sub-lane 0 computes fused coefficients.
__global__ void k_knn(const float4* __restrict__ pos4,
                      const float* __restrict__ attv,
                      const float* __restrict__ pos_skip,
                      const int* __restrict__ batch_skip,
                      const int* __restrict__ start,
                      int* __restrict__ knn_idx, float* __restrict__ knn_coef,
                      int Ny) {
    int gtid = blockIdx.x * blockDim.x + threadIdx.x;
    int i    = gtid >> 3;         // y index
    int sub  = gtid & (GL - 1);
    if (i >= Ny) return;

    float py0 = pos_skip[i * 3], py1 = pos_skip[i * 3 + 1], py2 = pos_skip[i * 3 + 2];
    int b = batch_skip[i];
    int s = start[b], e = start[b + 1];
    float ysq = py0 * py0 + py1 * py1 + py2 * py2;

    float d0 = 3.4e38f, d1 = 3.4e38f, d2 = 3.4e38f;
    int   i0 = 0x7fffffff, i1 = 0x7fffffff, i2 = 0x7fffffff;

    for (int j = s + sub; j < e; j += GL) {
        float4 v = pos4[j];
        float t = py0 * v.x;
        t = fmaf(py1, v.y, t);
        t = fmaf(py2, v.z, t);
        float dd = fmaf(-2.f, t, ysq + v.w);
        ins3f(dd, j, d0, i0, d1, i1, d2, i2);
    }

    #pragma unroll
    for (int off = 1; off < GL; off <<= 1) {
        float e0 = __shfl_xor(d0, off), e1 = __shfl_xor(d1, off), e2 = __shfl_xor(d2, off);
        int   j0 = __shfl_xor(i0, off), j1 = __shfl_xor(i1, off), j2 = __shfl_xor(i2, off);
        ins3t(e0, j0, d0, i0, d1, i1, d2, i2);
        ins3t(e1, j1, d0, i0, d1, i1, d2, i2);
        ins3t(e2, j2, d0, i0, d1, i1, d2, i2);
    }

    if (sub == 0) {
        int   jj[3] = { i0, i1, i2 };
        float w[3], a[3];
        #pragma unroll
        for (int t = 0; t < KNEI; ++t) {
            int j = (jj[t] == 0x7fffffff) ? 0 : jj[t];
            jj[t] = j;
            float4 v = pos4[j];
            float dx = v.x - py0;
            float dy = v.y - py1;
            float dz = v.z - py2;
            float sqd = dx * dx + dy * dy + dz * dz;
            w[t] = 1.f / fmaxf(sqd, 1e-16f);
            a[t] = attv[j];
        }
        float m  = fmaxf(a[0], fmaxf(a[1], a[2]));
        float e0s = expf(a[0] - m), e1s = expf(a[1] - m), e2s = expf(a[2] - m);
        float se  = e0s + e1s + e2s;
        float den = w[0] + w[1] + w[2];
        float inv = 1.f / (se * den);
        float c[3] = { w[0] * e0s * inv, w[1] * e1s * inv, w[2] * e2s * inv };
        #pragma unroll
        for (int t = 0; t < KNEI; ++t) {
            knn_idx[i * 3 + t]  = jj[t];
            knn_coef[i * 3 + t] = c[t];
        }
    }
}

// K2: h = [y || x_skip] @ W1 + b1, y-rows synthesized on the fly from the
// 3-neighbor gather. A-tile stored k-major in LDS so the inner loop is two
// ds_read_b128 (A read is a 4-address broadcast). Emits per-block column
// partial sum/sumsq for BN.
__global__ __launch_bounds__(256) void k_gemm(
    const float* __restrict__ x, const float* __restrict__ x_skip,
    const float* __restrict__ W1, const float* __restrict__ b1,
    const int* __restrict__ knn_idx, const float* __restrict__ knn_coef,
    float* __restrict__ hbuf, float* __restrict__ psum, float* __restrict__ psq,
    int Ny, int C, int Cs, int Co) {
    __shared__ __align__(16) float Ast[BK][BM + 4];   // k-major
    __shared__ __align__(16) float Bs[BK][BN + 4];

    const int mt = blockIdx.x, nt = blockIdx.y;
    const int rowbase = mt * BM, ncb = nt * BN;
    const int tid = threadIdx.x;
    const int tx = tid & 15, ty = tid >> 4;
    const int r = tid >> 2, q = tid & 3;   // staging: 4 threads per row/k
    const int Kin = C + Cs;

    const int grow = rowbase + r;
    const int   gi0 = knn_idx[grow * 3 + 0];
    const int   gi1 = knn_idx[grow * 3 + 1];
    const int   gi2 = knn_idx[grow * 3 + 2];
    const float gc0 = knn_coef[grow * 3 + 0];
    const float gc1 = knn_coef[grow * 3 + 1];
    const float gc2 = knn_coef[grow * 3 + 2];

    float acc[4][4] = {};

    for (int k0 = 0; k0 < Kin; k0 += BK) {
        // ---- stage A tile (64 rows x 64 k), transposed into Ast[k][m] ----
        if (k0 < C) {
            #pragma unroll
            for (int u = 0; u < 4; ++u) {
                int c = q * 16 + u * 4;
                float4 v0 = *reinterpret_cast<const float4*>(x + (size_t)gi0 * C + k0 + c);
                float4 v1 = *reinterpret_cast<const float4*>(x + (size_t)gi1 * C + k0 + c);
                float4 v2 = *reinterpret_cast<const float4*>(x + (size_t)gi2 * C + k0 + c);
                Ast[c + 0][r] = gc0 * v0.x + gc1 * v1.x + gc2 * v2.x;
                Ast[c + 1][r] = gc0 * v0.y + gc1 * v1.y + gc2 * v2.y;
                Ast[c + 2][r] = gc0 * v0.z + gc1 * v1.z + gc2 * v2.z;
                Ast[c + 3][r] = gc0 * v0.w + gc1 * v1.w + gc2 * v2.w;
            }
        } else {
            #pragma unroll
            for (int u = 0; u < 4; ++u) {
                int c = q * 16 + u * 4;
                float4 v = *reinterpret_cast<const float4*>(
                    x_skip + (size_t)grow * Cs + (k0 - C) + c);
                Ast[c + 0][r] = v.x;
                Ast[c + 1][r] = v.y;
                Ast[c + 2][r] = v.z;
                Ast[c + 3][r] = v.w;
            }
        }
        // ---- stage B tile (64 k x 64 n) ----
        #pragma unroll
        for (int u = 0; u < 4; ++u) {
            int c = q * 16 + u * 4;
            *reinterpret_cast<float4*>(&Bs[r][c]) =
                *reinterpret_cast<const float4*>(W1 + (size_t)(k0 + r) * Co + ncb + c);
        }
        __syncthreads();

        #pragma unroll 8
        for (int kk = 0; kk < BK; ++kk) {
            float4 av = *reinterpret_cast<const float4*>(&Ast[kk][ty * 4]);
            float4 bv = *reinterpret_cast<const float4*>(&Bs[kk][tx * 4]);
            acc[0][0] += av.x * bv.x; acc[0][1] += av.x * bv.y; acc[0][2] += av.x * bv.z; acc[0][3] += av.x * bv.w;
            acc[1][0] += av.y * bv.x; acc[1][1] += av.y * bv.y; acc[1][2] += av.y * bv.z; acc[1][3] += av.y * bv.w;
            acc[2][0] += av.z * bv.x; acc[2][1] += av.z * bv.y; acc[2][2] += av.z * bv.z; acc[2][3] += av.z * bv.w;
            acc[3][0] += av.w * bv.x; acc[3][1] += av.w * bv.y; acc[3][2] += av.w * bv.z; acc[3][3] += av.w * bv.w;
        }
        __syncthreads();
    }

    // ---- epilogue: +bias, write h, per-thread column stats ----
    float bb[4];
    #pragma unroll
    for (int n = 0; n < 4; ++n) bb[n] = b1[ncb + tx * 4 + n];

    float csum[4] = {}, csq[4] = {};
    #pragma unroll
    for (int m = 0; m < 4; ++m) {
        float4 hv;
        hv.x = acc[m][0] + bb[0];
        hv.y = acc[m][1] + bb[1];
        hv.z = acc[m][2] + bb[2];
        hv.w = acc[m][3] + bb[3];
        *reinterpret_cast<float4*>(hbuf + (size_t)(rowbase + ty * 4 + m) * Co + ncb + tx * 4) = hv;
        csum[0] += hv.x; csum[1] += hv.y; csum[2] += hv.z; csum[3] += hv.w;
        csq[0] += hv.x * hv.x; csq[1] += hv.y * hv.y; csq[2] += hv.z * hv.z; csq[3] += hv.w * hv.w;
    }

    __syncthreads();
    float* red = &Ast[0][0];  // scratch (>= 2048 floats)
    #pragma unroll
    for (int n = 0; n < 4; ++n) {
        red[(ty * 16 + tx) * 8 + n]     = csum[n];
        red[(ty * 16 + tx) * 8 + 4 + n] = csq[n];
    }
    __syncthreads();
    if (ty == 0) {
        float s[4] = {}, qq[4] = {};
        for (int yy = 0; yy < 16; ++yy) {
            #pragma unroll
            for (int n = 0; n < 4; ++n) {
                s[n]  += red[(yy * 16 + tx) * 8 + n];
                qq[n] += red[(yy * 16 + tx) * 8 + 4 + n];
            }
        }
        #pragma unroll
        for (int n = 0; n < 4; ++n) {
            psum[(size_t)mt * Co + ncb + tx * 4 + n] = s[n];
            psq [(size_t)mt * Co + ncb + tx * 4 + n] = qq[n];
        }
    }
}

// K3: reduce partials -> mean/var -> scale/shift per channel (1 block, 1024 thr)
__global__ void k_stats(const float* __restrict__ psum, const float* __restrict__ psq,
                        const float* __restrict__ gamma, const float* __restrict__ beta,
                        float* __restrict__ scale, float* __restrict__ shift,
                        int mtiles, int Co, int Ny) {
    __shared__ float sred[4][256], qred[4][256];
    int c  = threadIdx.x & 255;
    int ch = threadIdx.x >> 8;       // chunk 0..3
    int per = mtiles >> 2;
    float s = 0.f, q = 0.f;
    for (int m = ch * per; m < (ch + 1) * per; ++m) {
        s += psum[(size_t)m * Co + c];
        q += psq [(size_t)m * Co + c];
    }
    sred[ch][c] = s; qred[ch][c] = q;
    __syncthreads();
    if (ch == 0) {
        float S = ((sred[0][c] + sred[1][c]) + (sred[2][c] + sred[3][c]));
        float Q = ((qred[0][c] + qred[1][c]) + (qred[2][c] + qred[3][c]));
        float mean = S / (float)Ny;
        float var  = Q / (float)Ny - mean * mean;
        float rstd = rsqrtf(var + 1e-6f);
        float sc = gamma[c] * rstd;
        scale[c] = sc;
        shift[c] = beta[c] - mean * sc;
    }
}

// K4: in-place BN apply + LeakyReLU over h (float4)
__global__ void k_final(float* __restrict__ h, const float* __restrict__ scale,
                        const float* __restrict__ shift, int total4, int Co) {
    int t = blockIdx.x * blockDim.x + threadIdx.x;
    if (t >= total4) return;
    int c4 = (t & (Co / 4 - 1)) * 4;
    float4 v  = *reinterpret_cast<float4*>(h + (size_t)t * 4);
    float4 sc = *reinterpret_cast<const float4*>(scale + c4);
    float4 sh = *reinterpret_cast<const float4*>(shift + c4);
    v.x = v.x * sc.x + sh.x; v.x = v.x > 0.f ? v.x : 0.2f * v.x;
    v.y = v.y * sc.y + sh.y; v.y = v.y > 0.f ? v.y : 0.2f * v.y;
    v.z = v.z * sc.z + sh.z; v.z = v.z > 0.f ? v.z : 0.2f * v.z;
    v.w = v.w * sc.w + sh.w; v.w = v.w > 0.f ? v.w : 0.2f * v.w;
    *reinterpret_cast<float4*>(h + (size_t)t * 4) = v;
}

// K5: tail outputs: pos_skip copy + batch_skip as float
__global__ void k_tail(const float* __restrict__ pos_skip,
                       const int* __restrict__ batch_skip,
                       float* __restrict__ out_tail, int Ny) {
    int t = blockIdx.x * blockDim.x + threadIdx.x;
    int n3 = Ny * 3;
    if (t < n3) out_tail[t] = pos_skip[t];
    else if (t < n3 + Ny) out_tail[t] = (float)batch_skip[t - n3];
}

extern "C" void kernel_launch(void* const* d_in, const int* in_sizes, int n_in,
                              void* d_out, int out_size, void* d_ws, size_t ws_size,
                              hipStream_t stream) {
    const float* x         = (const float*)d_in[0];
    const float* pos       = (const float*)d_in[1];
    const int*   batch     = (const int*)d_in[2];
    const float* x_skip    = (const float*)d_in[3];
    const float* pos_skip  = (const float*)d_in[4];
    const int*   batch_skip= (const int*)d_in[5];
    const float* w_att     = (const float*)d_in[6];
    const float* W1        = (const float*)d_in[7];
    const float* b1        = (const float*)d_in[8];
    const float* gamma     = (const float*)d_in[9];
    const float* beta      = (const float*)d_in[10];

    const int Nx = in_sizes[2];
    const int Ny = in_sizes[5];
    const int C  = in_sizes[6];
    const int Co = in_sizes[8];
    const int Cs = in_sizes[3] / Ny;
    const int NB = 8;
    const int mtiles = Ny / BM;
    const int ntiles = Co / BN;

    char* w = (char*)d_ws;
    int*    start    = (int*)w;    w += 64;
    float*  attv     = (float*)w;  w += (size_t)Nx * 4;
    float4* pos4     = (float4*)w; w += (size_t)Nx * 16;
    int*    knn_idx  = (int*)w;    w += (size_t)Ny * 3 * 4;
    float*  knn_coef = (float*)w;  w += (size_t)Ny * 3 * 4;
    float*  psum     = (float*)w;  w += (size_t)mtiles * Co * 4;
    float*  psq      = (float*)w;  w += (size_t)mtiles * Co * 4;
    float*  scale    = (float*)w;  w += (size_t)Co * 4;
    float*  shift    = (float*)w;  w += (size_t)Co * 4;

    float* out      = (float*)d_out;
    float* hbuf     = out;                       // [Ny, Co]
    float* out_tail = out + (size_t)Ny * Co;     // pos_skip + batch_skip

    k_prep<<<dim3((Nx + 3) / 4), dim3(256), 0, stream>>>(x, pos, w_att, attv, pos4, Nx, C);
    k_start<<<dim3(1), dim3(64), 0, stream>>>(batch, start, Nx, NB);
    k_knn<<<dim3(Ny * GL / 256), dim3(256), 0, stream>>>(pos4, attv, pos_skip, batch_skip,
                                                         start, knn_idx, knn_coef, Ny);
    k_gemm<<<dim3(mtiles, ntiles), dim3(256), 0, stream>>>(x, x_skip, W1, b1, knn_idx, knn_coef,
                                                           hbuf, psum, psq, Ny, C, Cs, Co);
    k_stats<<<dim3(1), dim3(1024), 0, stream>>>(psum, psq, gamma, beta, scale, shift, mtiles, Co, Ny);
    k_final<<<dim3((Ny * Co / 4 + 255) / 256), dim3(256), 0, stream>>>(hbuf, scale, shift, Ny * Co / 4, Co);
    k_tail<<<dim3((Ny * 4 + 255) / 256), dim3(256), 0, stream>>>(pos_skip, batch_skip, out_tail, Ny);
}

// Round 4
// 107.590 us; speedup vs baseline: 2.5759x; 1.2909x over previous
//
#include <hip/hip_runtime.h>
#include <math.h>

// ---------------------------------------------------------------------------
// AttentiveFPModule: knn(K=3) attentive interpolate + concat + Linear + BN + LeakyReLU
// Sizes: Nx=4096, Ny=16384, C=256, Cs=128, Co=256, B=4, Kin=384
// GEMM path: bf16 MFMA 16x16x32, A pre-swizzled to fragment layout in global.
// ---------------------------------------------------------------------------

#define KNEI 3
#define GL 8            // lanes per y-point in k_knn
#define CIN 256         // C
#define CSK 128         // Cs
#define KIN 384         // C + Cs
#define CO  256         // Co
#define NKS 12          // KIN / 32
#define NNT 16          // CO / 16

typedef __attribute__((ext_vector_type(8))) short bf16x8;
typedef __attribute__((ext_vector_type(4))) float f32x4;

__device__ __forceinline__ ushort f2bf(float f) {
    unsigned u = __float_as_uint(f);
    u += 0x7fffu + ((u >> 16) & 1u);
    return (ushort)(u >> 16);
}

__device__ __forceinline__ bool nless(float da, int ia, float db, int ib) {
    return (da < db) || (da == db && ia < ib);
}

__device__ __forceinline__ void ins3f(float dd, int j,
                                      float& d0, int& i0,
                                      float& d1, int& i1,
                                      float& d2, int& i2) {
    bool l0 = dd < d0;
    bool l1 = dd < d1;
    bool l2 = dd < d2;
    float n2 = l1 ? d1 : (l2 ? dd : d2); int m2 = l1 ? i1 : (l2 ? j : i2);
    float n1 = l0 ? d0 : (l1 ? dd : d1); int m1 = l0 ? i0 : (l1 ? j : i1);
    float n0 = l0 ? dd : d0;             int m0 = l0 ? j  : i0;
    d0 = n0; i0 = m0; d1 = n1; i1 = m1; d2 = n2; i2 = m2;
}

__device__ __forceinline__ void ins3t(float dd, int j,
                                      float& d0, int& i0,
                                      float& d1, int& i1,
                                      float& d2, int& i2) {
    bool l0 = nless(dd, j, d0, i0);
    bool l1 = nless(dd, j, d1, i1);
    bool l2 = nless(dd, j, d2, i2);
    float n2 = l1 ? d1 : (l2 ? dd : d2); int m2 = l1 ? i1 : (l2 ? j : i2);
    float n1 = l0 ? d0 : (l1 ? dd : d1); int m1 = l0 ? i0 : (l1 ? j : i1);
    float n0 = l0 ? dd : d0;             int m0 = l0 ? j  : i0;
    d0 = n0; i0 = m0; d1 = n1; i1 = m1; d2 = n2; i2 = m2;
}

// K1 (multi-role by block range):
//   blocks [0, Nx/4): attv[j] = dot(x[j], w_att); pos4[j] = (pos, |pos|^2)
//   blocks [Nx/4, Nx/4+48): W1 -> Bbuf in MFMA B-fragment layout (bf16)
//   block  Nx/4+48: start[] = per-batch lower bounds
__global__ void k_prep(const float* __restrict__ x, const float* __restrict__ pos,
                       const float* __restrict__ w_att, const float* __restrict__ W1,
                       const int* __restrict__ batch,
                       float* __restrict__ attv, float4* __restrict__ pos4,
                       uint4* __restrict__ Bbuf, int* __restrict__ start,
                       int Nx, int NB) {
    int nb_x = Nx >> 2;
    int bid = blockIdx.x;
    int wave = threadIdx.x >> 6;
    int lane = threadIdx.x & 63;

    if (bid < nb_x) {
        int wid = bid * 4 + wave;
        float s = 0.f;
        for (int k = lane * 4; k < CIN; k += 256) {
            float4 xv = *reinterpret_cast<const float4*>(x + (size_t)wid * CIN + k);
            float4 wv = *reinterpret_cast<const float4*>(w_att + k);
            s += xv.x * wv.x + xv.y * wv.y + xv.z * wv.z + xv.w * wv.w;
        }
        #pragma unroll
        for (int off = 32; off; off >>= 1) s += __shfl_xor(s, off);
        if (lane == 0) {
            attv[wid] = s;
            float px = pos[wid * 3], py = pos[wid * 3 + 1], pz = pos[wid * 3 + 2];
            pos4[wid] = make_float4(px, py, pz, px * px + py * py + pz * pz);
        }
        return;
    }
    if (bid < nb_x + 48) {
        // B fragment: Bbuf[(ks*16+nt)*64 + lane] holds 8 bf16:
        //   elem j = W1[ks*32 + (lane>>4)*8 + j][nt*16 + (lane&15)]
        int p  = (bid - nb_x) * 4 + wave;      // 0..191
        int ks = p >> 4, nt = p & 15;
        int kb = ks * 32 + (lane >> 4) * 8;
        int n  = nt * 16 + (lane & 15);
        ushort u[8];
        #pragma unroll
        for (int j = 0; j < 8; ++j)
            u[j] = f2bf(W1[(size_t)(kb + j) * CO + n]);
        uint4 o;
        o.x = (unsigned)u[0] | ((unsigned)u[1] << 16);
        o.y = (unsigned)u[2] | ((unsigned)u[3] << 16);
        o.z = (unsigned)u[4] | ((unsigned)u[5] << 16);
        o.w = (unsigned)u[6] | ((unsigned)u[7] << 16);
        Bbuf[(size_t)(ks * 16 + nt) * 64 + lane] = o;
        return;
    }
    // start[]
    int b = threadIdx.x;
    if (b > NB) return;
    int lo = 0, hi = Nx;
    while (lo < hi) {
        int mid = (lo + hi) >> 1;
        if (batch[mid] < b) lo = mid + 1; else hi = mid;
    }
    start[b] = lo;
}

// K2: GL lanes per y point; branchless scan + butterfly merge.
__global__ void k_knn(const float4* __restrict__ pos4,
                      const float* __restrict__ attv,
                      const float* __restrict__ pos_skip,
                      const int* __restrict__ batch_skip,
                      const int* __restrict__ start,
                      int* __restrict__ knn_idx, float* __restrict__ knn_coef,
                      int Ny) {
    int gtid = blockIdx.x * blockDim.x + threadIdx.x;
    int i    = gtid >> 3;
    int sub  = gtid & (GL - 1);
    if (i >= Ny) return;

    float py0 = pos_skip[i * 3], py1 = pos_skip[i * 3 + 1], py2 = pos_skip[i * 3 + 2];
    int b = batch_skip[i];
    int s = start[b], e = start[b + 1];
    float ysq = py0 * py0 + py1 * py1 + py2 * py2;

    float d0 = 3.4e38f, d1 = 3.4e38f, d2 = 3.4e38f;
    int   i0 = 0x7fffffff, i1 = 0x7fffffff, i2 = 0x7fffffff;

    for (int j = s + sub; j < e; j += GL) {
        float4 v = pos4[j];
        float t = py0 * v.x;
        t = fmaf(py1, v.y, t);
        t = fmaf(py2, v.z, t);
        float dd = fmaf(-2.f, t, ysq + v.w);
        ins3f(dd, j, d0, i0, d1, i1, d2, i2);
    }

    #pragma unroll
    for (int off = 1; off < GL; off <<= 1) {
        float e0 = __shfl_xor(d0, off), e1 = __shfl_xor(d1, off), e2 = __shfl_xor(d2, off);
        int   j0 = __shfl_xor(i0, off), j1 = __shfl_xor(i1, off), j2 = __shfl_xor(i2, off);
        ins3t(e0, j0, d0, i0, d1, i1, d2, i2);
        ins3t(e1, j1, d0, i0, d1, i1, d2, i2);
        ins3t(e2, j2, d0, i0, d1, i1, d2, i2);
    }

    if (sub == 0) {
        int   jj[3] = { i0, i1, i2 };
        float w[3], a[3];
        #pragma unroll
        for (int t = 0; t < KNEI; ++t) {
            int j = (jj[t] == 0x7fffffff) ? 0 : jj[t];
            jj[t] = j;
            float4 v = pos4[j];
            float dx = v.x - py0;
            float dy = v.y - py1;
            float dz = v.z - py2;
            float sqd = dx * dx + dy * dy + dz * dz;
            w[t] = 1.f / fmaxf(sqd, 1e-16f);
            a[t] = attv[j];
        }
        float m  = fmaxf(a[0], fmaxf(a[1], a[2]));
        float e0s = expf(a[0] - m), e1s = expf(a[1] - m), e2s = expf(a[2] - m);
        float se  = e0s + e1s + e2s;
        float den = w[0] + w[1] + w[2];
        float inv = 1.f / (se * den);
        float c[3] = { w[0] * e0s * inv, w[1] * e1s * inv, w[2] * e2s * inv };
        #pragma unroll
        for (int t = 0; t < KNEI; ++t) {
            knn_idx[i * 3 + t]  = jj[t];
            knn_coef[i * 3 + t] = c[t];
        }
    }
}

// K3: materialize A = [y || x_skip] in bf16 MFMA A-fragment layout.
// Abuf[(strip*12 + ks)*64 + (row&15) + 16*kg] (uint4 = 8 bf16),
//   elem j = A[row][ks*32 + kg*8 + j].
// One wave per row; lane L in [0,48): k-chunk k0 = L*8 (ks=L>>2, kg=L&3).
__global__ void k_interp(const float* __restrict__ x, const float* __restrict__ x_skip,
                         const int* __restrict__ knn_idx, const float* __restrict__ knn_coef,
                         uint4* __restrict__ Abuf, int Ny) {
    int wave = threadIdx.x >> 6, lane = threadIdx.x & 63;
    int i = blockIdx.x * 4 + wave;
    if (i >= Ny || lane >= 48) return;
    int strip = i >> 4;
    int ks = lane >> 2, kg = lane & 3;
    int k0 = lane * 8;

    float v[8];
    if (k0 < CIN) {
        int gi0 = knn_idx[i * 3 + 0];
        int gi1 = knn_idx[i * 3 + 1];
        int gi2 = knn_idx[i * 3 + 2];
        float c0 = knn_coef[i * 3 + 0];
        float c1 = knn_coef[i * 3 + 1];
        float c2 = knn_coef[i * 3 + 2];
        const float4* p0 = reinterpret_cast<const float4*>(x + (size_t)gi0 * CIN + k0);
        const float4* p1 = reinterpret_cast<const float4*>(x + (size_t)gi1 * CIN + k0);
        const float4* p2 = reinterpret_cast<const float4*>(x + (size_t)gi2 * CIN + k0);
        #pragma unroll
        for (int h = 0; h < 2; ++h) {
            float4 a = p0[h], b = p1[h], c = p2[h];
            v[h * 4 + 0] = c0 * a.x + c1 * b.x + c2 * c.x;
            v[h * 4 + 1] = c0 * a.y + c1 * b.y + c2 * c.y;
            v[h * 4 + 2] = c0 * a.z + c1 * b.z + c2 * c.z;
            v[h * 4 + 3] = c0 * a.w + c1 * b.w + c2 * c.w;
        }
    } else {
        const float4* ps = reinterpret_cast<const float4*>(x_skip + (size_t)i * CSK + (k0 - CIN));
        #pragma unroll
        for (int h = 0; h < 2; ++h) {
            float4 a = ps[h];
            v[h * 4 + 0] = a.x; v[h * 4 + 1] = a.y; v[h * 4 + 2] = a.z; v[h * 4 + 3] = a.w;
        }
    }
    ushort u[8];
    #pragma unroll
    for (int j = 0; j < 8; ++j) u[j] = f2bf(v[j]);
    uint4 o;
    o.x = (unsigned)u[0] | ((unsigned)u[1] << 16);
    o.y = (unsigned)u[2] | ((unsigned)u[3] << 16);
    o.z = (unsigned)u[4] | ((unsigned)u[5] << 16);
    o.w = (unsigned)u[6] | ((unsigned)u[7] << 16);
    Abuf[(size_t)(strip * NKS + ks) * 64 + (i & 15) + 16 * kg] = o;
}

// K4: h = A @ W1 + b1 via bf16 MFMA. Block = 4 waves, 64 rows x 256 cols.
// A-frags straight from global (coalesced); B double-buffered in LDS.
// Emits per-block column partial sum/sumsq for BN (f32, pre-rounding acc).
__global__ __launch_bounds__(256) void k_gemm(
    const uint4* __restrict__ Abuf, const uint4* __restrict__ Bbuf,
    const float* __restrict__ b1, float* __restrict__ hbuf,
    float* __restrict__ psum, float* __restrict__ psq) {
    __shared__ uint4 Bls[2][1024];   // 2 x 16KB
    const int tid = threadIdx.x;
    const int wave = tid >> 6, lane = tid & 63;
    const int strip = blockIdx.x * 4 + wave;

    f32x4 acc[16];
    #pragma unroll
    for (int nt = 0; nt < NNT; ++nt) acc[nt] = (f32x4)(0.f);

    #pragma unroll
    for (int u = 0; u < 4; ++u) Bls[0][tid + 256 * u] = Bbuf[tid + 256 * u];
    __syncthreads();

    for (int ks = 0; ks < NKS; ++ks) {
        int cur = ks & 1;
        uint4 st[4];
        if (ks < NKS - 1) {
            #pragma unroll
            for (int u = 0; u < 4; ++u)
                st[u] = Bbuf[(size_t)(ks + 1) * 1024 + tid + 256 * u];
        }
        bf16x8 af = *reinterpret_cast<const bf16x8*>(
            Abuf + (size_t)(strip * NKS + ks) * 64 + lane);
        #pragma unroll
        for (int nt = 0; nt < NNT; ++nt) {
            bf16x8 bfr = *reinterpret_cast<const bf16x8*>(&Bls[cur][nt * 64 + lane]);
            acc[nt] = __builtin_amdgcn_mfma_f32_16x16x32_bf16(af, bfr, acc[nt], 0, 0, 0);
        }
        if (ks < NKS - 1) {
            #pragma unroll
            for (int u = 0; u < 4; ++u) Bls[cur ^ 1][tid + 256 * u] = st[u];
        }
        __syncthreads();
    }

    // epilogue: bias, store h (f32), per-column stats
    const int col16 = lane & 15, rg = lane >> 4;
    const int rowb = strip * 16 + rg * 4;
    float s_[16], q_[16];
    #pragma unroll
    for (int nt = 0; nt < NNT; ++nt) {
        float bn = b1[nt * 16 + col16];
        float s = 0.f, q = 0.f;
        #pragma unroll
        for (int r = 0; r < 4; ++r) {
            float v = acc[nt][r] + bn;
            hbuf[(size_t)(rowb + r) * CO + nt * 16 + col16] = v;
            s += v; q += v * v;
        }
        s += __shfl_xor(s, 16); s += __shfl_xor(s, 32);
        q += __shfl_xor(q, 16); q += __shfl_xor(q, 32);
        s_[nt] = s; q_[nt] = q;
    }
    float* S = reinterpret_cast<float*>(&Bls[0][0]);
    if (lane < 16) {
        #pragma unroll
        for (int nt = 0; nt < NNT; ++nt) {
            S[wave * 256 + nt * 16 + lane]        = s_[nt];
            S[1024 + wave * 256 + nt * 16 + lane] = q_[nt];
        }
    }
    __syncthreads();
    {
        float s = S[tid] + S[256 + tid] + S[512 + tid] + S[768 + tid];
        float q = S[1024 + tid] + S[1280 + tid] + S[1536 + tid] + S[1792 + tid];
        psum[(size_t)blockIdx.x * CO + tid] = s;
        psq [(size_t)blockIdx.x * CO + tid] = q;
    }
}

// K5: reduce partials -> mean/var -> scale/shift per channel (1 block, 1024 thr)
__global__ void k_stats(const float* __restrict__ psum, const float* __restrict__ psq,
                        const float* __restrict__ gamma, const float* __restrict__ beta,
                        float* __restrict__ scale, float* __restrict__ shift,
                        int mtiles, int Ny) {
    __shared__ float sred[4][256], qred[4][256];
    int c  = threadIdx.x & 255;
    int ch = threadIdx.x >> 8;
    int per = mtiles >> 2;
    float s = 0.f, q = 0.f;
    for (int m = ch * per; m < (ch + 1) * per; ++m) {
        s += psum[(size_t)m * CO + c];
        q += psq [(size_t)m * CO + c];
    }
    sred[ch][c] = s; qred[ch][c] = q;
    __syncthreads();
    if (ch == 0) {
        float S = ((sred[0][c] + sred[1][c]) + (sred[2][c] + sred[3][c]));
        float Q = ((qred[0][c] + qred[1][c]) + (qred[2][c] + qred[3][c]));
        float mean = S / (float)Ny;
        float var  = Q / (float)Ny - mean * mean;
        float rstd = rsqrtf(var + 1e-6f);
        float sc = gamma[c] * rstd;
        scale[c] = sc;
        shift[c] = beta[c] - mean * sc;
    }
}

// K6: BN apply + LeakyReLU over h (float4), plus tail (pos_skip copy,
// batch_skip as float) fused at the end of the grid.
__global__ void k_final(float* __restrict__ h, const float* __restrict__ scale,
                        const float* __restrict__ shift,
                        const float4* __restrict__ pos_skip4,
                        const int4* __restrict__ batch4,
                        float4* __restrict__ out_tail4,
                        int total4, int npos4, int ntail4) {
    int t = blockIdx.x * blockDim.x + threadIdx.x;
    if (t < total4) {
        int c4 = (t & (CO / 4 - 1)) * 4;
        float4 v  = *reinterpret_cast<float4*>(h + (size_t)t * 4);
        float4 sc = *reinterpret_cast<const float4*>(scale + c4);
        float4 sh = *reinterpret_cast<const float4*>(shift + c4);
        v.x = v.x * sc.x + sh.x; v.x = v.x > 0.f ? v.x : 0.2f * v.x;
        v.y = v.y * sc.y + sh.y; v.y = v.y > 0.f ? v.y : 0.2f * v.y;
        v.z = v.z * sc.z + sh.z; v.z = v.z > 0.f ? v.z : 0.2f * v.z;
        v.w = v.w * sc.w + sh.w; v.w = v.w > 0.f ? v.w : 0.2f * v.w;
        *reinterpret_cast<float4*>(h + (size_t)t * 4) = v;
    } else {
        int tt = t - total4;
        if (tt < npos4) {
            out_tail4[tt] = pos_skip4[tt];
        } else if (tt < ntail4) {
            int4 b = batch4[tt - npos4];
            out_tail4[tt] = make_float4((float)b.x, (float)b.y, (float)b.z, (float)b.w);
        }
    }
}

extern "C" void kernel_launch(void* const* d_in, const int* in_sizes, int n_in,
                              void* d_out, int out_size, void* d_ws, size_t ws_size,
                              hipStream_t stream) {
    const float* x         = (const float*)d_in[0];
    const float* pos       = (const float*)d_in[1];
    const int*   batch     = (const int*)d_in[2];
    const float* x_skip    = (const float*)d_in[3];
    const float* pos_skip  = (const float*)d_in[4];
    const int*   batch_skip= (const int*)d_in[5];
    const float* w_att     = (const float*)d_in[6];
    const float* W1        = (const float*)d_in[7];
    const float* b1        = (const float*)d_in[8];
    const float* gamma     = (const float*)d_in[9];
    const float* beta      = (const float*)d_in[10];

    const int Nx = in_sizes[2];      // 4096
    const int Ny = in_sizes[5];      // 16384
    const int NB = 8;
    const int strips  = Ny / 16;     // 1024
    const int gblocks = Ny / 64;     // 256 gemm blocks (= mtiles)

    // workspace layout (16B-aligned chunks first)
    char* w = (char*)d_ws;
    uint4*  Abuf     = (uint4*)w;  w += (size_t)strips * NKS * 64 * 16;   // 12.6 MB
    uint4*  Bbuf     = (uint4*)w;  w += (size_t)NKS * NNT * 64 * 16;      // 196 KB
    float4* pos4     = (float4*)w; w += (size_t)Nx * 16;
    float*  attv     = (float*)w;  w += (size_t)Nx * 4;
    int*    knn_idx  = (int*)w;    w += (size_t)Ny * 3 * 4;
    float*  knn_coef = (float*)w;  w += (size_t)Ny * 3 * 4;
    float*  psum     = (float*)w;  w += (size_t)gblocks * CO * 4;
    float*  psq      = (float*)w;  w += (size_t)gblocks * CO * 4;
    float*  scale    = (float*)w;  w += (size_t)CO * 4;
    float*  shift    = (float*)w;  w += (size_t)CO * 4;
    int*    start    = (int*)w;    w += 64;

    float* out      = (float*)d_out;
    float* hbuf     = out;                       // [Ny, Co] f32
    float* out_tail = out + (size_t)Ny * CO;

    const int total4 = Ny * CO / 4;
    const int npos4  = Ny * 3 / 4;
    const int ntail4 = npos4 + Ny / 4;   // 16384 float4s of tail output

    k_prep<<<dim3(Nx / 4 + 48 + 1), dim3(256), 0, stream>>>(
        x, pos, w_att, W1, batch, attv, pos4, Bbuf, start, Nx, NB);
    k_knn<<<dim3(Ny * GL / 256), dim3(256), 0, stream>>>(
        pos4, attv, pos_skip, batch_skip, start, knn_idx, knn_coef, Ny);
    k_interp<<<dim3(Ny / 4), dim3(256), 0, stream>>>(
        x, x_skip, knn_idx, knn_coef, Abuf, Ny);
    k_gemm<<<dim3(gblocks), dim3(256), 0, stream>>>(
        Abuf, Bbuf, b1, hbuf, psum, psq);
    k_stats<<<dim3(1), dim3(1024), 0, stream>>>(
        psum, psq, gamma, beta, scale, shift, gblocks, Ny);
    // grid covers total4 (BN apply) + ntail4 (pos_skip + batch_skip) threads
    k_final<<<dim3((total4 + ntail4 + 255) / 256), dim3(256), 0, stream>>>(
        hbuf, scale, shift, (const float4*)pos_skip, (const int4*)batch_skip,
        (float4*)out_tail, total4, npos4, ntail4);
}

// Round 5
// 78.285 us; speedup vs baseline: 3.5402x; 1.3743x over previous
//
#include <hip/hip_runtime.h>
#include <math.h>

// ---------------------------------------------------------------------------
// AttentiveFPModule: knn(K=3) attentive interpolate + concat + Linear + BN + LeakyReLU
// Sizes: Nx=4096, Ny=16384, C=256, Cs=128, Co=256, B=4, Kin=384
// GEMM path: bf16 MFMA 16x16x32, A pre-swizzled to fragment layout in global.
// ---------------------------------------------------------------------------

#define KNEI 3
#define GL 16           // lanes per y-point in k_knn
#define UNR 4           // scan unroll (independent loads in flight)
#define CIN 256         // C
#define CSK 128         // Cs
#define KIN 384         // C + Cs
#define CO  256         // Co
#define NKS 12          // KIN / 32
#define NNT 16          // CO / 16

typedef __attribute__((ext_vector_type(8))) short bf16x8;
typedef __attribute__((ext_vector_type(4))) float f32x4;

__device__ __forceinline__ ushort f2bf(float f) {
    unsigned u = __float_as_uint(f);
    u += 0x7fffu + ((u >> 16) & 1u);
    return (ushort)(u >> 16);
}

__device__ __forceinline__ bool nless(float da, int ia, float db, int ib) {
    return (da < db) || (da == db && ia < ib);
}

// Branchless insert, strict-less only (per-set candidates arrive in
// increasing index order, so '<' keeps the earliest index on ties).
__device__ __forceinline__ void ins3f(float dd, int j,
                                      float& d0, int& i0,
                                      float& d1, int& i1,
                                      float& d2, int& i2) {
    bool l0 = dd < d0;
    bool l1 = dd < d1;
    bool l2 = dd < d2;
    float n2 = l1 ? d1 : (l2 ? dd : d2); int m2 = l1 ? i1 : (l2 ? j : i2);
    float n1 = l0 ? d0 : (l1 ? dd : d1); int m1 = l0 ? i0 : (l1 ? j : i1);
    float n0 = l0 ? dd : d0;             int m0 = l0 ? j  : i0;
    d0 = n0; i0 = m0; d1 = n1; i1 = m1; d2 = n2; i2 = m2;
}

// Branchless insert with index tie-break (merge phase).
__device__ __forceinline__ void ins3t(float dd, int j,
                                      float& d0, int& i0,
                                      float& d1, int& i1,
                                      float& d2, int& i2) {
    bool l0 = nless(dd, j, d0, i0);
    bool l1 = nless(dd, j, d1, i1);
    bool l2 = nless(dd, j, d2, i2);
    float n2 = l1 ? d1 : (l2 ? dd : d2); int m2 = l1 ? i1 : (l2 ? j : i2);
    float n1 = l0 ? d0 : (l1 ? dd : d1); int m1 = l0 ? i0 : (l1 ? j : i1);
    float n0 = l0 ? dd : d0;             int m0 = l0 ? j  : i0;
    d0 = n0; i0 = m0; d1 = n1; i1 = m1; d2 = n2; i2 = m2;
}

// K1 (multi-role by block range):
//   blocks [0, Nx/4): attv[j] = dot(x[j], w_att); pos4[j] = (pos, |pos|^2)
//   blocks [Nx/4, Nx/4+48): W1 -> Bbuf in MFMA B-fragment layout (bf16)
//   block  Nx/4+48: start[] = per-batch lower bounds; zero pos4 pad
__global__ void k_prep(const float* __restrict__ x, const float* __restrict__ pos,
                       const float* __restrict__ w_att, const float* __restrict__ W1,
                       const int* __restrict__ batch,
                       float* __restrict__ attv, float4* __restrict__ pos4,
                       uint4* __restrict__ Bbuf, int* __restrict__ start,
                       int Nx, int NB) {
    int nb_x = Nx >> 2;
    int bid = blockIdx.x;
    int wave = threadIdx.x >> 6;
    int lane = threadIdx.x & 63;

    if (bid < nb_x) {
        int wid = bid * 4 + wave;
        float s = 0.f;
        for (int k = lane * 4; k < CIN; k += 256) {
            float4 xv = *reinterpret_cast<const float4*>(x + (size_t)wid * CIN + k);
            float4 wv = *reinterpret_cast<const float4*>(w_att + k);
            s += xv.x * wv.x + xv.y * wv.y + xv.z * wv.z + xv.w * wv.w;
        }
        #pragma unroll
        for (int off = 32; off; off >>= 1) s += __shfl_xor(s, off);
        if (lane == 0) {
            attv[wid] = s;
            float px = pos[wid * 3], py = pos[wid * 3 + 1], pz = pos[wid * 3 + 2];
            pos4[wid] = make_float4(px, py, pz, px * px + py * py + pz * pz);
        }
        return;
    }
    if (bid < nb_x + 48) {
        // B fragment: Bbuf[(ks*16+nt)*64 + lane] holds 8 bf16:
        //   elem j = W1[ks*32 + (lane>>4)*8 + j][nt*16 + (lane&15)]
        int p  = (bid - nb_x) * 4 + wave;      // 0..191
        int ks = p >> 4, nt = p & 15;
        int kb = ks * 32 + (lane >> 4) * 8;
        int n  = nt * 16 + (lane & 15);
        ushort u[8];
        #pragma unroll
        for (int j = 0; j < 8; ++j)
            u[j] = f2bf(W1[(size_t)(kb + j) * CO + n]);
        uint4 o;
        o.x = (unsigned)u[0] | ((unsigned)u[1] << 16);
        o.y = (unsigned)u[2] | ((unsigned)u[3] << 16);
        o.z = (unsigned)u[4] | ((unsigned)u[5] << 16);
        o.w = (unsigned)u[6] | ((unsigned)u[7] << 16);
        Bbuf[(size_t)(ks * 16 + nt) * 64 + lane] = o;
        return;
    }
    // start[] + pos4 pad zeroing
    int t = threadIdx.x;
    if (t < 64) {
        int b = t;
        if (b > NB) return;
        int lo = 0, hi = Nx;
        while (lo < hi) {
            int mid = (lo + hi) >> 1;
            if (batch[mid] < b) lo = mid + 1; else hi = mid;
        }
        start[b] = lo;
    } else if (t < 128) {
        pos4[Nx + (t - 64)] = make_float4(0.f, 0.f, 0.f, 0.f);
    }
}

// K2: GL lanes per y point; 4-wide unrolled branchless scan with two
// independent top-3 sets (A: candidates 0,2 mod 4; B: 1,3 mod 4), then
// B->A merge and 4-stage butterfly across the 16-lane group.
__global__ void k_knn(const float4* __restrict__ pos4,
                      const float* __restrict__ attv,
                      const float* __restrict__ pos_skip,
                      const int* __restrict__ batch_skip,
                      const int* __restrict__ start,
                      int* __restrict__ knn_idx, float* __restrict__ knn_coef,
                      int Ny) {
    int gtid = blockIdx.x * blockDim.x + threadIdx.x;
    int i    = gtid >> 4;
    int sub  = gtid & (GL - 1);
    if (i >= Ny) return;

    float py0 = pos_skip[i * 3], py1 = pos_skip[i * 3 + 1], py2 = pos_skip[i * 3 + 2];
    int bb = batch_skip[i];
    int s = start[bb], e = start[bb + 1];
    float ysq = py0 * py0 + py1 * py1 + py2 * py2;

    const float FBIG = 3.38e38f;
    float a0 = __int_as_float(0x7f800000), a1 = a0, a2 = a0;   // +inf
    float b0 = a0, b1 = a0, b2 = a0;
    int   ia0 = 0x7fffffff, ia1 = 0x7fffffff, ia2 = 0x7fffffff;
    int   ib0 = 0x7fffffff, ib1 = 0x7fffffff, ib2 = 0x7fffffff;

    for (int jb = s + sub; jb < e; jb += GL * UNR) {
        int j0 = jb, j1 = jb + GL, j2 = jb + 2 * GL, j3 = jb + 3 * GL;
        float4 v0 = pos4[j0];
        float4 v1 = pos4[j1];
        float4 v2 = pos4[j2];
        float4 v3 = pos4[j3];
        float t0 = fmaf(py2, v0.z, fmaf(py1, v0.y, py0 * v0.x));
        float t1 = fmaf(py2, v1.z, fmaf(py1, v1.y, py0 * v1.x));
        float t2 = fmaf(py2, v2.z, fmaf(py1, v2.y, py0 * v2.x));
        float t3 = fmaf(py2, v3.z, fmaf(py1, v3.y, py0 * v3.x));
        float dd0 = fmaf(-2.f, t0, ysq + v0.w);
        float dd1 = fmaf(-2.f, t1, ysq + v1.w);
        float dd2 = fmaf(-2.f, t2, ysq + v2.w);
        float dd3 = fmaf(-2.f, t3, ysq + v3.w);
        dd1 = (j1 < e) ? dd1 : FBIG;                   // j0 valid by loop cond
        dd2 = (j2 < e) ? dd2 : FBIG;
        dd3 = (j3 < e) ? dd3 : FBIG;
        ins3f(dd0, j0, a0, ia0, a1, ia1, a2, ia2);
        ins3f(dd1, j1, b0, ib0, b1, ib1, b2, ib2);
        ins3f(dd2, j2, a0, ia0, a1, ia1, a2, ia2);
        ins3f(dd3, j3, b0, ib0, b1, ib1, b2, ib2);
    }

    // merge set B into set A (indices distinct; tie-break on index)
    ins3t(b0, ib0, a0, ia0, a1, ia1, a2, ia2);
    ins3t(b1, ib1, a0, ia0, a1, ia1, a2, ia2);
    ins3t(b2, ib2, a0, ia0, a1, ia1, a2, ia2);

    #pragma unroll
    for (int off = 1; off < GL; off <<= 1) {
        float e0 = __shfl_xor(a0, off), e1 = __shfl_xor(a1, off), e2 = __shfl_xor(a2, off);
        int   j0 = __shfl_xor(ia0, off), j1 = __shfl_xor(ia1, off), j2 = __shfl_xor(ia2, off);
        ins3t(e0, j0, a0, ia0, a1, ia1, a2, ia2);
        ins3t(e1, j1, a0, ia0, a1, ia1, a2, ia2);
        ins3t(e2, j2, a0, ia0, a1, ia1, a2, ia2);
    }

    if (sub == 0) {
        int   jj[3] = { ia0, ia1, ia2 };
        float w[3], a[3];
        #pragma unroll
        for (int t = 0; t < KNEI; ++t) {
            int j = (jj[t] == 0x7fffffff) ? 0 : jj[t];
            jj[t] = j;
            float4 v = pos4[j];
            float dx = v.x - py0;
            float dy = v.y - py1;
            float dz = v.z - py2;
            float sqd = dx * dx + dy * dy + dz * dz;
            w[t] = 1.f / fmaxf(sqd, 1e-16f);
            a[t] = attv[j];
        }
        float m  = fmaxf(a[0], fmaxf(a[1], a[2]));
        float e0s = expf(a[0] - m), e1s = expf(a[1] - m), e2s = expf(a[2] - m);
        float se  = e0s + e1s + e2s;
        float den = w[0] + w[1] + w[2];
        float inv = 1.f / (se * den);
        float c[3] = { w[0] * e0s * inv, w[1] * e1s * inv, w[2] * e2s * inv };
        #pragma unroll
        for (int t = 0; t < KNEI; ++t) {
            knn_idx[i * 3 + t]  = jj[t];
            knn_coef[i * 3 + t] = c[t];
        }
    }
}

// K3: materialize A = [y || x_skip] in bf16 MFMA A-fragment layout.
// Abuf[(strip*12 + ks)*64 + (row&15) + 16*kg] (uint4 = 8 bf16),
//   elem j = A[row][ks*32 + kg*8 + j].
// One wave per row; lane L in [0,48): k-chunk k0 = L*8 (ks=L>>2, kg=L&3).
__global__ void k_interp(const float* __restrict__ x, const float* __restrict__ x_skip,
                         const int* __restrict__ knn_idx, const float* __restrict__ knn_coef,
                         uint4* __restrict__ Abuf, int Ny) {
    int wave = threadIdx.x >> 6, lane = threadIdx.x & 63;
    int i = blockIdx.x * 4 + wave;
    if (i >= Ny || lane >= 48) return;
    int strip = i >> 4;
    int ks = lane >> 2, kg = lane & 3;
    int k0 = lane * 8;

    float v[8];
    if (k0 < CIN) {
        int gi0 = knn_idx[i * 3 + 0];
        int gi1 = knn_idx[i * 3 + 1];
        int gi2 = knn_idx[i * 3 + 2];
        float c0 = knn_coef[i * 3 + 0];
        float c1 = knn_coef[i * 3 + 1];
        float c2 = knn_coef[i * 3 + 2];
        const float4* p0 = reinterpret_cast<const float4*>(x + (size_t)gi0 * CIN + k0);
        const float4* p1 = reinterpret_cast<const float4*>(x + (size_t)gi1 * CIN + k0);
        const float4* p2 = reinterpret_cast<const float4*>(x + (size_t)gi2 * CIN + k0);
        #pragma unroll
        for (int h = 0; h < 2; ++h) {
            float4 a = p0[h], b = p1[h], c = p2[h];
            v[h * 4 + 0] = c0 * a.x + c1 * b.x + c2 * c.x;
            v[h * 4 + 1] = c0 * a.y + c1 * b.y + c2 * c.y;
            v[h * 4 + 2] = c0 * a.z + c1 * b.z + c2 * c.z;
            v[h * 4 + 3] = c0 * a.w + c1 * b.w + c2 * c.w;
        }
    } else {
        const float4* ps = reinterpret_cast<const float4*>(x_skip + (size_t)i * CSK + (k0 - CIN));
        #pragma unroll
        for (int h = 0; h < 2; ++h) {
            float4 a = ps[h];
            v[h * 4 + 0] = a.x; v[h * 4 + 1] = a.y; v[h * 4 + 2] = a.z; v[h * 4 + 3] = a.w;
        }
    }
    ushort u[8];
    #pragma unroll
    for (int j = 0; j < 8; ++j) u[j] = f2bf(v[j]);
    uint4 o;
    o.x = (unsigned)u[0] | ((unsigned)u[1] << 16);
    o.y = (unsigned)u[2] | ((unsigned)u[3] << 16);
    o.z = (unsigned)u[4] | ((unsigned)u[5] << 16);
    o.w = (unsigned)u[6] | ((unsigned)u[7] << 16);
    Abuf[(size_t)(strip * NKS + ks) * 64 + (i & 15) + 16 * kg] = o;
}

// K4: h = A @ W1 + b1 via bf16 MFMA. Block = 4 waves, 64 rows x 256 cols.
// A-frags straight from global (coalesced); B double-buffered in LDS.
// Emits per-block column partial sum/sumsq for BN (f32, pre-rounding acc).
__global__ __launch_bounds__(256) void k_gemm(
    const uint4* __restrict__ Abuf, const uint4* __restrict__ Bbuf,
    const float* __restrict__ b1, float* __restrict__ hbuf,
    float* __restrict__ psum, float* __restrict__ psq) {
    __shared__ uint4 Bls[2][1024];   // 2 x 16KB
    const int tid = threadIdx.x;
    const int wave = tid >> 6, lane = tid & 63;
    const int strip = blockIdx.x * 4 + wave;

    f32x4 acc[16];
    #pragma unroll
    for (int nt = 0; nt < NNT; ++nt) acc[nt] = (f32x4)(0.f);

    #pragma unroll
    for (int u = 0; u < 4; ++u) Bls[0][tid + 256 * u] = Bbuf[tid + 256 * u];
    __syncthreads();

    for (int ks = 0; ks < NKS; ++ks) {
        int cur = ks & 1;
        uint4 st[4];
        if (ks < NKS - 1) {
            #pragma unroll
            for (int u = 0; u < 4; ++u)
                st[u] = Bbuf[(size_t)(ks + 1) * 1024 + tid + 256 * u];
        }
        bf16x8 af = *reinterpret_cast<const bf16x8*>(
            Abuf + (size_t)(strip * NKS + ks) * 64 + lane);
        #pragma unroll
        for (int nt = 0; nt < NNT; ++nt) {
            bf16x8 bfr = *reinterpret_cast<const bf16x8*>(&Bls[cur][nt * 64 + lane]);
            acc[nt] = __builtin_amdgcn_mfma_f32_16x16x32_bf16(af, bfr, acc[nt], 0, 0, 0);
        }
        if (ks < NKS - 1) {
            #pragma unroll
            for (int u = 0; u < 4; ++u) Bls[cur ^ 1][tid + 256 * u] = st[u];
        }
        __syncthreads();
    }

    // epilogue: bias, store h (f32), per-column stats
    const int col16 = lane & 15, rg = lane >> 4;
    const int rowb = strip * 16 + rg * 4;
    float s_[16], q_[16];
    #pragma unroll
    for (int nt = 0; nt < NNT; ++nt) {
        float bn = b1[nt * 16 + col16];
        float s = 0.f, q = 0.f;
        #pragma unroll
        for (int r = 0; r < 4; ++r) {
            float v = acc[nt][r] + bn;
            hbuf[(size_t)(rowb + r) * CO + nt * 16 + col16] = v;
            s += v; q += v * v;
        }
        s += __shfl_xor(s, 16); s += __shfl_xor(s, 32);
        q += __shfl_xor(q, 16); q += __shfl_xor(q, 32);
        s_[nt] = s; q_[nt] = q;
    }
    float* S = reinterpret_cast<float*>(&Bls[0][0]);
    if (lane < 16) {
        #pragma unroll
        for (int nt = 0; nt < NNT; ++nt) {
            S[wave * 256 + nt * 16 + lane]        = s_[nt];
            S[1024 + wave * 256 + nt * 16 + lane] = q_[nt];
        }
    }
    __syncthreads();
    {
        float s = S[tid] + S[256 + tid] + S[512 + tid] + S[768 + tid];
        float q = S[1024 + tid] + S[1280 + tid] + S[1536 + tid] + S[1792 + tid];
        psum[(size_t)blockIdx.x * CO + tid] = s;
        psq [(size_t)blockIdx.x * CO + tid] = q;
    }
}

// K5: reduce partials -> mean/var -> scale/shift per channel (1 block, 1024 thr)
__global__ void k_stats(const float* __restrict__ psum, const float* __restrict__ psq,
                        const float* __restrict__ gamma, const float* __restrict__ beta,
                        float* __restrict__ scale, float* __restrict__ shift,
                        int mtiles, int Ny) {
    __shared__ float sred[4][256], qred[4][256];
    int c  = threadIdx.x & 255;
    int ch = threadIdx.x >> 8;
    int per = mtiles >> 2;
    float s = 0.f, q = 0.f;
    for (int m = ch * per; m < (ch + 1) * per; ++m) {
        s += psum[(size_t)m * CO + c];
        q += psq [(size_t)m * CO + c];
    }
    sred[ch][c] = s; qred[ch][c] = q;
    __syncthreads();
    if (ch == 0) {
        float S = ((sred[0][c] + sred[1][c]) + (sred[2][c] + sred[3][c]));
        float Q = ((qred[0][c] + qred[1][c]) + (qred[2][c] + qred[3][c]));
        float mean = S / (float)Ny;
        float var  = Q / (float)Ny - mean * mean;
        float rstd = rsqrtf(var + 1e-6f);
        float sc = gamma[c] * rstd;
        scale[c] = sc;
        shift[c] = beta[c] - mean * sc;
    }
}

// K6: BN apply + LeakyReLU over h (float4), plus tail (pos_skip copy,
// batch_skip as float) fused at the end of the grid.
__global__ void k_final(float* __restrict__ h, const float* __restrict__ scale,
                        const float* __restrict__ shift,
                        const float4* __restrict__ pos_skip4,
                        const int4* __restrict__ batch4,
                        float4* __restrict__ out_tail4,
                        int total4, int npos4, int ntail4) {
    int t = blockIdx.x * blockDim.x + threadIdx.x;
    if (t < total4) {
        int c4 = (t & (CO / 4 - 1)) * 4;
        float4 v  = *reinterpret_cast<float4*>(h + (size_t)t * 4);
        float4 sc = *reinterpret_cast<const float4*>(scale + c4);
        float4 sh = *reinterpret_cast<const float4*>(shift + c4);
        v.x = v.x * sc.x + sh.x; v.x = v.x > 0.f ? v.x : 0.2f * v.x;
        v.y = v.y * sc.y + sh.y; v.y = v.y > 0.f ? v.y : 0.2f * v.y;
        v.z = v.z * sc.z + sh.z; v.z = v.z > 0.f ? v.z : 0.2f * v.z;
        v.w = v.w * sc.w + sh.w; v.w = v.w > 0.f ? v.w : 0.2f * v.w;
        *reinterpret_cast<float4*>(h + (size_t)t * 4) = v;
    } else {
        int tt = t - total4;
        if (tt < npos4) {
            out_tail4[tt] = pos_skip4[tt];
        } else if (tt < ntail4) {
            int4 b = batch4[tt - npos4];
            out_tail4[tt] = make_float4((float)b.x, (float)b.y, (float)b.z, (float)b.w);
        }
    }
}

extern "C" void kernel_launch(void* const* d_in, const int* in_sizes, int n_in,
                              void* d_out, int out_size, void* d_ws, size_t ws_size,
                              hipStream_t stream) {
    const float* x         = (const float*)d_in[0];
    const float* pos       = (const float*)d_in[1];
    const int*   batch     = (const int*)d_in[2];
    const float* x_skip    = (const float*)d_in[3];
    const float* pos_skip  = (const float*)d_in[4];
    const int*   batch_skip= (const int*)d_in[5];
    const float* w_att     = (const float*)d_in[6];
    const float* W1        = (const float*)d_in[7];
    const float* b1        = (const float*)d_in[8];
    const float* gamma     = (const float*)d_in[9];
    const float* beta      = (const float*)d_in[10];

    const int Nx = in_sizes[2];      // 4096
    const int Ny = in_sizes[5];      // 16384
    const int NB = 8;
    const int strips  = Ny / 16;     // 1024
    const int gblocks = Ny / 64;     // 256 gemm blocks (= mtiles)

    // workspace layout (16B-aligned chunks first)
    char* w = (char*)d_ws;
    uint4*  Abuf     = (uint4*)w;  w += (size_t)strips * NKS * 64 * 16;   // 12.6 MB
    uint4*  Bbuf     = (uint4*)w;  w += (size_t)NKS * NNT * 64 * 16;      // 196 KB
    float4* pos4     = (float4*)w; w += (size_t)(Nx + 64) * 16;           // +64 pad
    float*  attv     = (float*)w;  w += (size_t)Nx * 4;
    int*    knn_idx  = (int*)w;    w += (size_t)Ny * 3 * 4;
    float*  knn_coef = (float*)w;  w += (size_t)Ny * 3 * 4;
    float*  psum     = (float*)w;  w += (size_t)gblocks * CO * 4;
    float*  psq      = (float*)w;  w += (size_t)gblocks * CO * 4;
    float*  scale    = (float*)w;  w += (size_t)CO * 4;
    float*  shift    = (float*)w;  w += (size_t)CO * 4;
    int*    start    = (int*)w;    w += 64;

    float* out      = (float*)d_out;
    float* hbuf     = out;                       // [Ny, Co] f32
    float* out_tail = out + (size_t)Ny * CO;

    const int total4 = Ny * CO / 4;
    const int npos4  = Ny * 3 / 4;
    const int ntail4 = npos4 + Ny / 4;   // 16384 float4s of tail output

    k_prep<<<dim3(Nx / 4 + 48 + 1), dim3(256), 0, stream>>>(
        x, pos, w_att, W1, batch, attv, pos4, Bbuf, start, Nx, NB);
    k_knn<<<dim3(Ny * GL / 256), dim3(256), 0, stream>>>(
        pos4, attv, pos_skip, batch_skip, start, knn_idx, knn_coef, Ny);
    k_interp<<<dim3(Ny / 4), dim3(256), 0, stream>>>(
        x, x_skip, knn_idx, knn_coef, Abuf, Ny);
    k_gemm<<<dim3(gblocks), dim3(256), 0, stream>>>(
        Abuf, Bbuf, b1, hbuf, psum, psq);
    k_stats<<<dim3(1), dim3(1024), 0, stream>>>(
        psum, psq, gamma, beta, scale, shift, gblocks, Ny);
    // grid covers total4 (BN apply) + ntail4 (pos_skip + batch_skip) threads
    k_final<<<dim3((total4 + ntail4 + 255) / 256), dim3(256), 0, stream>>>(
        hbuf, scale, shift, (const float4*)pos_skip, (const int4*)batch_skip,
        (float4*)out_tail, total4, npos4, ntail4);
}